// Round 11
// baseline (485.346 us; speedup 1.0000x reference)
//
#include <hip/hip_runtime.h>
#include <hip/hip_fp16.h>
#include <stdint.h>

// Problem constants (fixed: M=N=K=4096).
// Harness buffer reality (proven r5-r8): x,lut,out are float32; packed_weight
// is int32 holding ONE byte per element (hi nibble = even k, lo nibble = odd k).
#define M_DIM 4096
#define N_DIM 4096
#define K_DIM 4096
#define KW (K_DIM / 2)
#define WS_XH_BYTES ((size_t)M_DIM * K_DIM * 2)  // 32 MB: x as fp16
#define WS_WH_BYTES ((size_t)N_DIM * K_DIM * 2)  // 32 MB: W as fp16

typedef _Float16 half8 __attribute__((ext_vector_type(8)));   // 4 VGPRs (MFMA A/B)
typedef float f32x4 __attribute__((ext_vector_type(4)));      // MFMA accumulator

__device__ __forceinline__ uint32_t pk2(float a, float b) {
  // packed f32->f16 RTZ (exact: every input value is fp16-representable)
  auto h = __builtin_amdgcn_cvt_pkrtz(a, b);  // a -> low halfword
  return __builtin_bit_cast(uint32_t, h);
}

// Dequant one packed byte -> u32 (fp16 even-k | fp16 odd-k << 16) via v_perm
// byte lookup in an 8-byte magnitude pool. [proven bit-exact r6-r8]
__device__ __forceinline__ uint32_t dq(uint32_t b, uint32_t ph, uint32_t pl) {
#if __has_builtin(__builtin_amdgcn_perm)
  const uint32_t sel = ((b & 0x70u) << 4) | ((b & 0x07u) << 24);
  uint32_t v = __builtin_amdgcn_perm(ph, pl, sel);  // bytes 4-7 = ph, 0-3 = pl
#else
  const uint64_t pool = ((uint64_t)ph << 32) | pl;
  const uint32_t mh = (uint32_t)(pool >> (((b >> 4) & 7u) * 8)) & 0xFFu;
  const uint32_t ml = (uint32_t)(pool >> ((b & 7u) * 8)) & 0xFFu;
  uint32_t v = (mh << 8) | (ml << 24);
#endif
  const uint32_t sg = ((b & 0x88u) * 0x10000100u) & 0x80008000u;  // b7->15, b3->31
  return v | sg;
}

__device__ __forceinline__ void lut_pool(const float* __restrict__ lutf,
                                         uint32_t& ph, uint32_t& pl) {
  const uint32_t h01 = pk2(lutf[0], lutf[1]);
  const uint32_t h23 = pk2(lutf[2], lutf[3]);
  const uint32_t h45 = pk2(lutf[4], lutf[5]);
  const uint32_t h67 = pk2(lutf[6], lutf[7]);
#if __has_builtin(__builtin_amdgcn_perm)
  pl = __builtin_amdgcn_perm(h23, h01, 0x07050301u);
  ph = __builtin_amdgcn_perm(h67, h45, 0x07050301u);
#else
  pl = ((h01 >> 8) & 0xFFu) | ((h01 >> 24) << 8) |
       (((h23 >> 8) & 0xFFu) << 16) | ((h23 >> 24) << 24);
  ph = ((h45 >> 8) & 0xFFu) | ((h45 >> 24) << 8) |
       (((h67 >> 8) & 0xFFu) << 16) | ((h67 >> 24) << 24);
#endif
}

// Fused pre-pass (r13): blocks [0,8192) convert x f32->f16; blocks [8192,16384)
// dequant W packed->f16. One launch, both streams concurrent; 160 MB traffic.
#define XBLOCKS (M_DIM * K_DIM / 8 / 256)   // 8192
#define WBLOCKS (N_DIM * KW / 4 / 256)      // 8192

__global__ __launch_bounds__(256) void prep_kernel(
    const float4* __restrict__ xin, uint4* __restrict__ xout,
    const int4* __restrict__ pin, uint4* __restrict__ wout,
    const float* __restrict__ lutf) {
  const int b = blockIdx.x;
  if (b < XBLOCKS) {
    const int i = b * 256 + threadIdx.x;   // uint4 index
    const float4 v0 = xin[2 * i];
    const float4 v1 = xin[2 * i + 1];
    xout[i] = make_uint4(pk2(v0.x, v0.y), pk2(v0.z, v0.w),
                         pk2(v1.x, v1.y), pk2(v1.z, v1.w));
  } else {
    uint32_t ph, pl;
    lut_pool(lutf, ph, pl);
    const int i = (b - XBLOCKS) * 256 + threadIdx.x;  // int4 index
    const int4 w = pin[i];
    wout[i] = make_uint4(dq(w.x, ph, pl), dq(w.y, ph, pl),
                         dq(w.z, ph, pl), dq(w.w, ph, pl));
  }
}

// Pre-pass (fallback path only): x f32 -> fp16.
__global__ __launch_bounds__(256) void cvt_x_kernel(const float4* __restrict__ xin,
                                                    uint4* __restrict__ xout) {
  const int i = blockIdx.x * 256 + threadIdx.x;
  const float4 v0 = xin[2 * i];
  const float4 v1 = xin[2 * i + 1];
  xout[i] = make_uint4(pk2(v0.x, v0.y), pk2(v0.z, v0.w),
                       pk2(v1.x, v1.y), pk2(v1.z, v1.w));
}

__device__ __forceinline__ f32x4 mfma16(half8 a, half8 b, f32x4 c) {
  return __builtin_amdgcn_mfma_f32_16x16x32_f16(a, b, c, 0, 0, 0);
}

// ---------------------------------------------------------------------------
// Round 21: A BYPASSES LDS — fragments loaded register-direct from global
// (L2-resident under the XCD swizzle). r10 post-mortem: minimal-head SGB
// regressed (serialized MFMA behind its own read) — r8 reverted-to; and the
// corrected pipe model shows the LDS pipe (frag reads 96 KB + GLL writes
// 32 KB ~ 1450 cy/phase) — not MFMA (1242) — is the r8 floor. A's x4 wm-share
// amplification is structural while A transits LDS. Bypass: an A fragment is
// 16 CONTIGUOUS global bytes/lane (16 fully-consumed 64B lines/wave); af[m]'s
// next-phase load issues right after row m's MFMAs consume the old value
// (register WAR at issue; A genuinely dies per-row — unlike r9's B), giving a
// full phase of latency cover with ZERO extra VGPRs.
// New per-phase floors: LDS ~575 cy (B only), VMEM ~1000 (A, L2-hit),
// MFMA 1242 — independent pipes.
// Ledger (walked, in-order vmcnt retirement): B-only staging, 2 GLL/phase,
// 2-phase depth. Phase-end vmcnt(10): newest 10 = {this phase's 2 stage GLL +
// 8 af loads}; everything older — including the B half-tile the NEXT phase
// reads — is retired. Prologue: B0(0),B1(0),B0(1) + af(kh0,t0); vmcnt(12)
// retires B0(0). Compiler-inserted waits cover af RAW. Barriers/WAR as r8:
// stage targets were last read one phase earlier, separated by a barrier.
// LDS now 64 KB (B only). XOR chunk swizzle on B unchanged (0 conflicts).
// SGB guide: [DS 4][VMEM 2] head, then ([MFMA 4][VMEM 1])x8 per phase.
// ---------------------------------------------------------------------------
#define NT (K_DIM / 64)
#define SGB __builtin_amdgcn_sched_group_barrier
#define SG_MFMA 0x8
#define SG_VMEM 0x10
#define SG_DSRD 0x100

__global__ __launch_bounds__(512, 2) void f16gemm256_kernel(
    const uint8_t* __restrict__ xh,    // fp16 bits [M, K] (ws + 0)
    const uint8_t* __restrict__ wh,    // fp16 bits [N, K] (ws + 32MB)
    float* __restrict__ out)           // [M, N] float32
{
  __shared__ uint16_t Bl[2][2][256 * 32];   // [buf][kh][row][chunk*8+e], 64 KB

  const int tid  = threadIdx.x;
  const int lane = tid & 63;
  const int wave = tid >> 6;           // 0..7
  const int wm   = wave >> 2;          // 0..1  (128-row half of M tile)
  const int wn   = wave & 3;           // 0..3  (64-col quarter of N tile)

  // Bijective XCD swizzle: 256 blocks, 8 XCDs, 32 blocks each.
  const int bid = blockIdx.x;
  const int sw  = (bid & 7) * 32 + (bid >> 3);
  const int m0  = (sw >> 4) * 256;
  const int n0  = (sw & 15) * 256;

  // B staging geometry: slot = tid + s*512 over a 1024-slot (16 KB) region;
  // phys slot (row, cc) sources global chunk cc ^ ((row>>1)&3).
  const uint8_t* bsrc[2];
  int ldst[2];
#pragma unroll
  for (int s = 0; s < 2; ++s) {
    const int slot = tid + s * 512;
    const int row  = slot >> 2;
    const int g    = (slot & 3) ^ ((row >> 1) & 3);
    bsrc[s] = wh + ((size_t)(n0 + row) * K_DIM) * 2 + g * 16;
    ldst[s] = slot * 16;
  }

  auto STAGEB = [&](int buf, int kh, int tt) {
    const int koff  = tt * 128 + kh * 64;   // global k byte offset
    uint8_t* lb = (uint8_t*)&Bl[0][0][0] + (buf * 2 + kh) * 16384;
#pragma unroll
    for (int s = 0; s < 2; ++s) {
      __builtin_amdgcn_global_load_lds(
          (const __attribute__((address_space(1))) uint32_t*)(bsrc[s] + koff),
          (__attribute__((address_space(3))) uint32_t*)(lb + ldst[s]), 16, 0, 0);
    }
  };

  // B fragment read offsets (u16 units within a (buf,kh) region).
  int boff[4];
#pragma unroll
  for (int n = 0; n < 4; ++n) {
    const int row = wn * 64 + n * 16 + (lane & 15);
    const int ch  = (lane >> 4) ^ ((row >> 1) & 3);
    boff[n] = row * 32 + ch * 8;
  }

  // A register-direct base: row = m0 + wm*128 + m*16 + (lane&15),
  // byte = row*8192 + t*128 + kh*64 + (lane>>4)*16. 16B contiguous per lane.
  const uint8_t* Ax = xh + (size_t)(m0 + wm * 128 + (lane & 15)) * (K_DIM * 2)
                         + (lane >> 4) * 16;

  f32x4 acc[8][4];
#pragma unroll
  for (int i = 0; i < 8; ++i)
#pragma unroll
    for (int j = 0; j < 4; ++j) acc[i][j] = (f32x4){0.f, 0.f, 0.f, 0.f};

  half8 af[8], bfr[4];

  // Prologue: stage B0(0), B1(0), B0(1) [6 GLL]; load af <- A kh0(0) [8];
  // vmcnt(12) retires B0(0); barrier publishes.
  STAGEB(0, 0, 0);
  STAGEB(0, 1, 0);
  STAGEB(1, 0, 1);
#pragma unroll
  for (int m = 0; m < 8; ++m)
    af[m] = *(const half8*)(Ax + m * (16 * K_DIM * 2));
  asm volatile("s_waitcnt vmcnt(12)" ::: "memory");
  __builtin_amdgcn_s_barrier();

#pragma unroll 2
  for (int t = 0; t < NT; ++t) {
    const int cur = t & 1;
    const uint16_t* Bb = &Bl[cur][0][0];
    const bool st1 = (t + 1 < NT);
    const bool st2 = (t + 2 < NT);

    // ===== phase alpha: kh0 MFMAs (af = kh0(t)); af reloads <- kh1(t) =====
    __builtin_amdgcn_s_setprio(1);
    bfr[0] = *(const half8*)(Bb + boff[0]);
    bfr[1] = *(const half8*)(Bb + boff[1]);
    bfr[2] = *(const half8*)(Bb + boff[2]);
    bfr[3] = *(const half8*)(Bb + boff[3]);
    if (st1) STAGEB(cur ^ 1, 1, t + 1);
#pragma unroll
    for (int m = 0; m < 8; ++m) {
      acc[m][0] = mfma16(af[m], bfr[0], acc[m][0]);
      acc[m][1] = mfma16(af[m], bfr[1], acc[m][1]);
      acc[m][2] = mfma16(af[m], bfr[2], acc[m][2]);
      acc[m][3] = mfma16(af[m], bfr[3], acc[m][3]);
      af[m] = *(const half8*)(Ax + m * (16 * K_DIM * 2) + t * 128 + 64);  // kh1(t)
    }
    SGB(SG_DSRD, 4, 0);
    SGB(SG_VMEM, 2, 0);
#pragma unroll
    for (int i = 0; i < 8; ++i) { SGB(SG_MFMA, 4, 0); SGB(SG_VMEM, 1, 0); }
    __builtin_amdgcn_s_setprio(0);
    asm volatile("s_waitcnt vmcnt(10)" ::: "memory");
    __builtin_amdgcn_s_barrier();

    // ===== phase beta: kh1 MFMAs (af = kh1(t)); af reloads <- kh0(t+1) =====
    __builtin_amdgcn_s_setprio(1);
    bfr[0] = *(const half8*)(Bb + 8192 + boff[0]);
    bfr[1] = *(const half8*)(Bb + 8192 + boff[1]);
    bfr[2] = *(const half8*)(Bb + 8192 + boff[2]);
    bfr[3] = *(const half8*)(Bb + 8192 + boff[3]);
    if (st2) STAGEB(cur, 0, t + 2);
#pragma unroll
    for (int m = 0; m < 8; ++m) {
      acc[m][0] = mfma16(af[m], bfr[0], acc[m][0]);
      acc[m][1] = mfma16(af[m], bfr[1], acc[m][1]);
      acc[m][2] = mfma16(af[m], bfr[2], acc[m][2]);
      acc[m][3] = mfma16(af[m], bfr[3], acc[m][3]);
      if (st1)
        af[m] = *(const half8*)(Ax + m * (16 * K_DIM * 2) + (t + 1) * 128);  // kh0(t+1)
    }
    SGB(SG_DSRD, 4, 0);
    SGB(SG_VMEM, 2, 0);
#pragma unroll
    for (int i = 0; i < 8; ++i) { SGB(SG_MFMA, 4, 0); SGB(SG_VMEM, 1, 0); }
    __builtin_amdgcn_s_setprio(0);
    asm volatile("s_waitcnt vmcnt(10)" ::: "memory");
    __builtin_amdgcn_s_barrier();
  }

  // ---- Epilogue: C/D layout col(n) = lane&15, row(m) = (lane>>4)*4 + r ----
  const int mb = m0 + wm * 128 + (lane >> 4) * 4;
  const int nb = n0 + wn * 64 + (lane & 15);
#pragma unroll
  for (int m = 0; m < 8; ++m)
#pragma unroll
    for (int n = 0; n < 4; ++n)
#pragma unroll
      for (int r = 0; r < 4; ++r)
        out[(size_t)(mb + m * 16 + r) * N_DIM + (nb + n * 16)] = acc[m][n][r];
}

// ---------------------------------------------------------------------------
// Fallback (r9 champion): 128x128, in-loop B dequant — used only if d_ws is
// too small for both fp16 operands.
// ---------------------------------------------------------------------------
#define BM 128
#define BN 128
#define BK 32

__global__ __launch_bounds__(256, 2) void fp4gemm_kernel(
    const uint8_t* __restrict__ xh, const int* __restrict__ pw,
    const float* __restrict__ lutf, float* __restrict__ out)
{
  __shared__ uint16_t ldsA[BM * BK];
  __shared__ uint16_t ldsB[BN * BK];

  const int tid  = threadIdx.x;
  const int lane = tid & 63;
  const int wave = tid >> 6;
  const int wm   = wave >> 1;
  const int wn   = wave & 1;
  const int m0 = blockIdx.y * BM;
  const int n0 = blockIdx.x * BN;

  uint32_t ph, pl;
  lut_pool(lutf, ph, pl);

  f32x4 acc[4][4];
#pragma unroll
  for (int i = 0; i < 4; ++i)
#pragma unroll
    for (int j = 0; j < 4; ++j) acc[i][j] = (f32x4){0.f, 0.f, 0.f, 0.f};

  const int rowB  = tid >> 1;
  const int halfB = tid & 1;
  const int swzB  = (rowB >> 1) & 3;

  for (int kt = 0; kt < K_DIM / BK; ++kt) {
    __syncthreads();

#pragma unroll
    for (int s = 0; s < 2; ++s) {
      const int idx = tid + s * 256;
      const int row = idx >> 2;
      const int c16 = idx & 3;
      const int g16 = c16 ^ ((row >> 1) & 3);
      const uint8_t* gp = xh + ((size_t)(m0 + row) * K_DIM + kt * BK) * 2 + g16 * 16;
      uint8_t* lp = (uint8_t*)ldsA + (size_t)idx * 16;
      __builtin_amdgcn_global_load_lds(
          (const __attribute__((address_space(1))) uint32_t*)gp,
          (__attribute__((address_space(3))) uint32_t*)lp, 16, 0, 0);
    }

    {
      const int* gp = pw + (size_t)(n0 + rowB) * KW + kt * (BK / 2) + halfB * 8;
      const int4 wA = ((const int4*)gp)[0];
      const int4 wB = ((const int4*)gp)[1];
      uint8_t* base = (uint8_t*)ldsB + rowB * 64;
      *(uint4*)(base + ((halfB * 2 + 0) ^ swzB) * 16) =
          make_uint4(dq(wA.x, ph, pl), dq(wA.y, ph, pl),
                     dq(wA.z, ph, pl), dq(wA.w, ph, pl));
      *(uint4*)(base + ((halfB * 2 + 1) ^ swzB) * 16) =
          make_uint4(dq(wB.x, ph, pl), dq(wB.y, ph, pl),
                     dq(wB.z, ph, pl), dq(wB.w, ph, pl));
    }

    __syncthreads();

    const int q = lane >> 4;
    half8 af[4], bfr[4];
#pragma unroll
    for (int i = 0; i < 4; ++i) {
      const int row = wm * 64 + i * 16 + (lane & 15);
      af[i] = *(const half8*)(ldsA + row * BK + (q ^ ((row >> 1) & 3)) * 8);
    }
#pragma unroll
    for (int j = 0; j < 4; ++j) {
      const int row = wn * 64 + j * 16 + (lane & 15);
      bfr[j] = *(const half8*)(ldsB + row * BK + (q ^ ((row >> 1) & 3)) * 8);
    }
#pragma unroll
    for (int i = 0; i < 4; ++i)
#pragma unroll
      for (int j = 0; j < 4; ++j)
        acc[i][j] = __builtin_amdgcn_mfma_f32_16x16x32_f16(af[i], bfr[j], acc[i][j], 0, 0, 0);
  }

  const int mb = m0 + wm * 64 + (lane >> 4) * 4;
  const int nb = n0 + wn * 64 + (lane & 15);
#pragma unroll
  for (int i = 0; i < 4; ++i)
#pragma unroll
    for (int j = 0; j < 4; ++j)
#pragma unroll
      for (int r = 0; r < 4; ++r)
        out[(size_t)(mb + i * 16 + r) * N_DIM + (nb + j * 16)] = acc[i][j][r];
}

extern "C" void kernel_launch(void* const* d_in, const int* in_sizes, int n_in,
                              void* d_out, int out_size, void* d_ws, size_t ws_size,
                              hipStream_t stream) {
  // Size-based dispatch (element counts are dtype-independent and unique).
  const void* px = nullptr; const void* ppw = nullptr; const void* plut = nullptr;
  for (int i = 0; i < n_in; ++i) {
    const long s = in_sizes[i];
    if (s == (long)M_DIM * K_DIM) px = d_in[i];
    else if (s == (long)N_DIM * KW) ppw = d_in[i];
    else if (s == 16) plut = d_in[i];
  }
  if (!px || !ppw || !plut) { px = d_in[0]; ppw = d_in[1]; plut = d_in[2]; }

  if (ws_size >= WS_XH_BYTES + WS_WH_BYTES) {
    // Fused prep: x f32->f16 into ws[0,32MB) and W fp4->f16 into ws[32MB,64MB).
    uint8_t* wh = (uint8_t*)d_ws + WS_XH_BYTES;
    prep_kernel<<<XBLOCKS + WBLOCKS, 256, 0, stream>>>(
        (const float4*)px, (uint4*)d_ws, (const int4*)ppw, (uint4*)wh,
        (const float*)plut);
    f16gemm256_kernel<<<dim3(256), dim3(512), 0, stream>>>(
        (const uint8_t*)d_ws, wh, (float*)d_out);
  } else {
    cvt_x_kernel<<<(M_DIM * K_DIM / 8) / 256, 256, 0, stream>>>(
        (const float4*)px, (uint4*)d_ws);
    dim3 grid(N_DIM / BN, M_DIM / BM);
    fp4gemm_kernel<<<grid, dim3(256), 0, stream>>>(
        (const uint8_t*)d_ws, (const int*)ppw, (const float*)plut, (float*)d_out);
  }
}

// Round 12
// 251.038 us; speedup vs baseline: 1.9334x; 1.9334x over previous
//
#include <hip/hip_runtime.h>
#include <hip/hip_fp16.h>
#include <stdint.h>

// Problem constants (fixed: M=N=K=4096).
// Harness buffer reality (proven r5-r8): x,lut,out are float32; packed_weight
// is int32 holding ONE byte per element (hi nibble = even k, lo nibble = odd k).
#define M_DIM 4096
#define N_DIM 4096
#define K_DIM 4096
#define KW (K_DIM / 2)
#define WS_XH_BYTES ((size_t)M_DIM * K_DIM * 2)  // 32 MB: x as fp16
#define WS_WH_BYTES ((size_t)N_DIM * K_DIM * 2)  // 32 MB: W as fp16

typedef _Float16 half8 __attribute__((ext_vector_type(8)));   // 4 VGPRs (MFMA A/B)
typedef float f32x4 __attribute__((ext_vector_type(4)));      // MFMA accumulator

__device__ __forceinline__ uint32_t pk2(float a, float b) {
  // packed f32->f16 RTZ (exact: every input value is fp16-representable)
  auto h = __builtin_amdgcn_cvt_pkrtz(a, b);  // a -> low halfword
  return __builtin_bit_cast(uint32_t, h);
}

// Dequant one packed byte -> u32 (fp16 even-k | fp16 odd-k << 16) via v_perm
// byte lookup in an 8-byte magnitude pool. [proven bit-exact r6-r8]
__device__ __forceinline__ uint32_t dq(uint32_t b, uint32_t ph, uint32_t pl) {
#if __has_builtin(__builtin_amdgcn_perm)
  const uint32_t sel = ((b & 0x70u) << 4) | ((b & 0x07u) << 24);
  uint32_t v = __builtin_amdgcn_perm(ph, pl, sel);  // bytes 4-7 = ph, 0-3 = pl
#else
  const uint64_t pool = ((uint64_t)ph << 32) | pl;
  const uint32_t mh = (uint32_t)(pool >> (((b >> 4) & 7u) * 8)) & 0xFFu;
  const uint32_t ml = (uint32_t)(pool >> ((b & 7u) * 8)) & 0xFFu;
  uint32_t v = (mh << 8) | (ml << 24);
#endif
  const uint32_t sg = ((b & 0x88u) * 0x10000100u) & 0x80008000u;  // b7->15, b3->31
  return v | sg;
}

__device__ __forceinline__ void lut_pool(const float* __restrict__ lutf,
                                         uint32_t& ph, uint32_t& pl) {
  const uint32_t h01 = pk2(lutf[0], lutf[1]);
  const uint32_t h23 = pk2(lutf[2], lutf[3]);
  const uint32_t h45 = pk2(lutf[4], lutf[5]);
  const uint32_t h67 = pk2(lutf[6], lutf[7]);
#if __has_builtin(__builtin_amdgcn_perm)
  pl = __builtin_amdgcn_perm(h23, h01, 0x07050301u);
  ph = __builtin_amdgcn_perm(h67, h45, 0x07050301u);
#else
  pl = ((h01 >> 8) & 0xFFu) | ((h01 >> 24) << 8) |
       (((h23 >> 8) & 0xFFu) << 16) | ((h23 >> 24) << 24);
  ph = ((h45 >> 8) & 0xFFu) | ((h45 >> 24) << 8) |
       (((h67 >> 8) & 0xFFu) << 16) | ((h67 >> 24) << 24);
#endif
}

// Fused pre-pass (r13): blocks [0,8192) convert x f32->f16; blocks [8192,16384)
// dequant W packed->f16. One launch, both streams concurrent; 160 MB traffic.
#define XBLOCKS (M_DIM * K_DIM / 8 / 256)   // 8192
#define WBLOCKS (N_DIM * KW / 4 / 256)      // 8192

__global__ __launch_bounds__(256) void prep_kernel(
    const float4* __restrict__ xin, uint4* __restrict__ xout,
    const int4* __restrict__ pin, uint4* __restrict__ wout,
    const float* __restrict__ lutf) {
  const int b = blockIdx.x;
  if (b < XBLOCKS) {
    const int i = b * 256 + threadIdx.x;   // uint4 index
    const float4 v0 = xin[2 * i];
    const float4 v1 = xin[2 * i + 1];
    xout[i] = make_uint4(pk2(v0.x, v0.y), pk2(v0.z, v0.w),
                         pk2(v1.x, v1.y), pk2(v1.z, v1.w));
  } else {
    uint32_t ph, pl;
    lut_pool(lutf, ph, pl);
    const int i = (b - XBLOCKS) * 256 + threadIdx.x;  // int4 index
    const int4 w = pin[i];
    wout[i] = make_uint4(dq(w.x, ph, pl), dq(w.y, ph, pl),
                         dq(w.z, ph, pl), dq(w.w, ph, pl));
  }
}

// Pre-pass (fallback path only): x f32 -> fp16.
__global__ __launch_bounds__(256) void cvt_x_kernel(const float4* __restrict__ xin,
                                                    uint4* __restrict__ xout) {
  const int i = blockIdx.x * 256 + threadIdx.x;
  const float4 v0 = xin[2 * i];
  const float4 v1 = xin[2 * i + 1];
  xout[i] = make_uint4(pk2(v0.x, v0.y), pk2(v0.z, v0.w),
                       pk2(v1.x, v1.y), pk2(v1.z, v1.w));
}

__device__ __forceinline__ f32x4 mfma16(half8 a, half8 b, f32x4 c) {
  return __builtin_amdgcn_mfma_f32_16x16x32_f16(a, b, c, 0, 0, 0);
}

// ---------------------------------------------------------------------------
// Round 22 = r8 CHAMPION RESTORED (118.1us GEMM, MfmaUtil 53.2, 0 conflicts).
// Session constraint map (r9/r10/r11 post-mortems, each closing a branch):
//  - r9: kh0 B-frags live through all 32 kh0 MFMAs -> kh1 B reads can't hoist
//    (register WAR); merged phase + vmcnt(0) drain = 130us. Closed.
//  - r10: [DS 1][MFMA 1] fine pairing serializes MFMA behind its own read's
//    LDS latency = 136us. Closed.
//  - r11: register-direct global A is VMEM-latency-bound at 2 waves/SIMD
//    (465 GB/s, MfmaUtil 15%) = 363us. Closed.
//  - r7: acc[8][4](128) + 124 VGPR = 252 ~ the hard 256-reg cap (512-thread
//    block => 8 waves co-resident on 4 SIMDs => <=256 regs/wave, regardless
//    of launch_bounds). Cross-phase fragment prefetch spills. Closed.
// r8 phase model: 2214 cy = LDS pipe ~1450 (96KB frag reads + 32KB GLL
// writes) vs MFMA 1242, partially overlapped by rolling rows + 2-wave drift.
// Schedule: alpha/beta phases per BK=64 tile; head {bfr0-3, af0, af1}; rows
// m=0..7 with af[m+2] read between rows; SGB [DS6]([DS1][MFMA4])x6[MFMA4]x2.
// Ledger (walked): prologue stages 6 half-tiles, vmcnt(8) retires {B0,A0}(0);
// alpha(t) stages B1A1(t+1)->cur^1, vmcnt(8) retires {B1,A1}(t); beta(t)
// stages B0A0(t+2)->cur, vmcnt(8) retires {B0,A0}(t+1); tail vmcnt(0)/(4).
// XOR chunk swizzle (r9): phys chunk = logical ^ ((row>>1)&3) on the GLL
// *source* (dest linear, rule 21); frag reads 2-way/bank = free.
// ---------------------------------------------------------------------------
#define NT (K_DIM / 64)
#define SGB __builtin_amdgcn_sched_group_barrier
#define SG_MFMA 0x8
#define SG_VMEM 0x10
#define SG_DSRD 0x100

__global__ __launch_bounds__(512, 2) void f16gemm256_kernel(
    const uint8_t* __restrict__ xh,    // fp16 bits [M, K] (ws + 0)
    const uint8_t* __restrict__ wh,    // fp16 bits [N, K] (ws + 32MB)
    float* __restrict__ out)           // [M, N] float32
{
  __shared__ uint16_t Al[2][2][256 * 32];   // [buf][kh][row][chunk*8+e]
  __shared__ uint16_t Bl[2][2][256 * 32];

  const int tid  = threadIdx.x;
  const int lane = tid & 63;
  const int wave = tid >> 6;           // 0..7
  const int wm   = wave >> 2;          // 0..1  (128-row half of M tile)
  const int wn   = wave & 3;           // 0..3  (64-col quarter of N tile)

  // Bijective XCD swizzle: 256 blocks, 8 XCDs, 32 blocks each.
  const int bid = blockIdx.x;
  const int sw  = (bid & 7) * 32 + (bid >> 3);
  const int m0  = (sw >> 4) * 256;
  const int n0  = (sw & 15) * 256;

  // Staging geometry: slot = tid + s*512 over a 1024-slot (16 KB) region;
  // phys slot (row, cc) sources global chunk cc ^ ((row>>1)&3).
  const uint8_t* asrc[2];
  const uint8_t* bsrc[2];
  int ldst[2];
#pragma unroll
  for (int s = 0; s < 2; ++s) {
    const int slot = tid + s * 512;
    const int row  = slot >> 2;
    const int g    = (slot & 3) ^ ((row >> 1) & 3);
    asrc[s] = xh + ((size_t)(m0 + row) * K_DIM) * 2 + g * 16;
    bsrc[s] = wh + ((size_t)(n0 + row) * K_DIM) * 2 + g * 16;
    ldst[s] = slot * 16;
  }

  auto STAGE = [&](int isB, int buf, int kh, int tt) {
    const int koff  = tt * 128 + kh * 64;   // global k byte offset
    uint8_t* lb = (uint8_t*)(isB ? &Bl[0][0][0] : &Al[0][0][0]) +
                  (buf * 2 + kh) * 16384;
#pragma unroll
    for (int s = 0; s < 2; ++s) {
      const uint8_t* gp = (isB ? bsrc[s] : asrc[s]) + koff;
      __builtin_amdgcn_global_load_lds(
          (const __attribute__((address_space(1))) uint32_t*)gp,
          (__attribute__((address_space(3))) uint32_t*)(lb + ldst[s]), 16, 0, 0);
    }
  };

  // Per-thread fragment read offsets (u16 units within a (buf,kh) region).
  int aoff[8], boff[4];
#pragma unroll
  for (int m = 0; m < 8; ++m) {
    const int row = wm * 128 + m * 16 + (lane & 15);
    const int ch  = (lane >> 4) ^ ((row >> 1) & 3);
    aoff[m] = row * 32 + ch * 8;
  }
#pragma unroll
  for (int n = 0; n < 4; ++n) {
    const int row = wn * 64 + n * 16 + (lane & 15);
    const int ch  = (lane >> 4) ^ ((row >> 1) & 3);
    boff[n] = row * 32 + ch * 8;
  }

  f32x4 acc[8][4];
#pragma unroll
  for (int i = 0; i < 8; ++i)
#pragma unroll
    for (int j = 0; j < 4; ++j) acc[i][j] = (f32x4){0.f, 0.f, 0.f, 0.f};

  // Prologue: stage B0A0(0), B1A1(0), B0A0(1); vmcnt(8) retires B0A0(0).
  STAGE(1, 0, 0, 0);
  STAGE(0, 0, 0, 0);
  STAGE(1, 0, 1, 0);
  STAGE(0, 0, 1, 0);
  STAGE(1, 1, 0, 1);
  STAGE(0, 1, 0, 1);
  asm volatile("s_waitcnt vmcnt(8)" ::: "memory");
  __builtin_amdgcn_s_barrier();

  half8 af[8], bfr[4];

#pragma unroll 2
  for (int t = 0; t < NT; ++t) {
    const int cur = t & 1;
    const uint16_t* Ab = &Al[cur][0][0];
    const uint16_t* Bb = &Bl[cur][0][0];
    const bool st1 = (t + 1 < NT);
    const bool st2 = (t + 2 < NT);

    // ===== phase alpha: kh=0 — rolling-row pipeline =====
    __builtin_amdgcn_s_setprio(1);
    bfr[0] = *(const half8*)(Bb + boff[0]);
    bfr[1] = *(const half8*)(Bb + boff[1]);
    bfr[2] = *(const half8*)(Bb + boff[2]);
    bfr[3] = *(const half8*)(Bb + boff[3]);
    af[0] = *(const half8*)(Ab + aoff[0]);
    af[1] = *(const half8*)(Ab + aoff[1]);
    SGB(SG_DSRD, 6, 0);                       // head group
    if (st1) { STAGE(1, cur ^ 1, 1, t + 1); STAGE(0, cur ^ 1, 1, t + 1); }
#pragma unroll
    for (int m = 0; m < 8; ++m) {
      if (m + 2 < 8) {
        af[m + 2] = *(const half8*)(Ab + aoff[m + 2]);
        SGB(SG_DSRD, 1, 0);                   // af[m+2] fills under row m
      }
      acc[m][0] = mfma16(af[m], bfr[0], acc[m][0]);
      acc[m][1] = mfma16(af[m], bfr[1], acc[m][1]);
      acc[m][2] = mfma16(af[m], bfr[2], acc[m][2]);
      acc[m][3] = mfma16(af[m], bfr[3], acc[m][3]);
      SGB(SG_MFMA, 4, 0);
    }
    __builtin_amdgcn_s_setprio(0);
    if (st1) asm volatile("s_waitcnt vmcnt(8)" ::: "memory");
    else     asm volatile("s_waitcnt vmcnt(0)" ::: "memory");
    __builtin_amdgcn_s_barrier();

    // ===== phase beta: kh=1 — rolling-row pipeline =====
    __builtin_amdgcn_s_setprio(1);
    bfr[0] = *(const half8*)(Bb + 8192 + boff[0]);
    bfr[1] = *(const half8*)(Bb + 8192 + boff[1]);
    bfr[2] = *(const half8*)(Bb + 8192 + boff[2]);
    bfr[3] = *(const half8*)(Bb + 8192 + boff[3]);
    af[0] = *(const half8*)(Ab + 8192 + aoff[0]);
    af[1] = *(const half8*)(Ab + 8192 + aoff[1]);
    SGB(SG_DSRD, 6, 0);
    if (st2) { STAGE(1, cur, 0, t + 2); STAGE(0, cur, 0, t + 2); }
#pragma unroll
    for (int m = 0; m < 8; ++m) {
      if (m + 2 < 8) {
        af[m + 2] = *(const half8*)(Ab + 8192 + aoff[m + 2]);
        SGB(SG_DSRD, 1, 0);
      }
      acc[m][0] = mfma16(af[m], bfr[0], acc[m][0]);
      acc[m][1] = mfma16(af[m], bfr[1], acc[m][1]);
      acc[m][2] = mfma16(af[m], bfr[2], acc[m][2]);
      acc[m][3] = mfma16(af[m], bfr[3], acc[m][3]);
      SGB(SG_MFMA, 4, 0);
    }
    __builtin_amdgcn_s_setprio(0);
    if (st2)      asm volatile("s_waitcnt vmcnt(8)" ::: "memory");
    else if (st1) asm volatile("s_waitcnt vmcnt(4)" ::: "memory");
    __builtin_amdgcn_s_barrier();
  }

  // ---- Epilogue: C/D layout col(n) = lane&15, row(m) = (lane>>4)*4 + r ----
  const int mb = m0 + wm * 128 + (lane >> 4) * 4;
  const int nb = n0 + wn * 64 + (lane & 15);
#pragma unroll
  for (int m = 0; m < 8; ++m)
#pragma unroll
    for (int n = 0; n < 4; ++n)
#pragma unroll
      for (int r = 0; r < 4; ++r)
        out[(size_t)(mb + m * 16 + r) * N_DIM + (nb + n * 16)] = acc[m][n][r];
}

// ---------------------------------------------------------------------------
// Fallback (r9 champion): 128x128, in-loop B dequant — used only if d_ws is
// too small for both fp16 operands.
// ---------------------------------------------------------------------------
#define BM 128
#define BN 128
#define BK 32

__global__ __launch_bounds__(256, 2) void fp4gemm_kernel(
    const uint8_t* __restrict__ xh, const int* __restrict__ pw,
    const float* __restrict__ lutf, float* __restrict__ out)
{
  __shared__ uint16_t ldsA[BM * BK];
  __shared__ uint16_t ldsB[BN * BK];

  const int tid  = threadIdx.x;
  const int lane = tid & 63;
  const int wave = tid >> 6;
  const int wm   = wave >> 1;
  const int wn   = wave & 1;
  const int m0 = blockIdx.y * BM;
  const int n0 = blockIdx.x * BN;

  uint32_t ph, pl;
  lut_pool(lutf, ph, pl);

  f32x4 acc[4][4];
#pragma unroll
  for (int i = 0; i < 4; ++i)
#pragma unroll
    for (int j = 0; j < 4; ++j) acc[i][j] = (f32x4){0.f, 0.f, 0.f, 0.f};

  const int rowB  = tid >> 1;
  const int halfB = tid & 1;
  const int swzB  = (rowB >> 1) & 3;

  for (int kt = 0; kt < K_DIM / BK; ++kt) {
    __syncthreads();

#pragma unroll
    for (int s = 0; s < 2; ++s) {
      const int idx = tid + s * 256;
      const int row = idx >> 2;
      const int c16 = idx & 3;
      const int g16 = c16 ^ ((row >> 1) & 3);
      const uint8_t* gp = xh + ((size_t)(m0 + row) * K_DIM + kt * BK) * 2 + g16 * 16;
      uint8_t* lp = (uint8_t*)ldsA + (size_t)idx * 16;
      __builtin_amdgcn_global_load_lds(
          (const __attribute__((address_space(1))) uint32_t*)gp,
          (__attribute__((address_space(3))) uint32_t*)lp, 16, 0, 0);
    }

    {
      const int* gp = pw + (size_t)(n0 + rowB) * KW + kt * (BK / 2) + halfB * 8;
      const int4 wA = ((const int4*)gp)[0];
      const int4 wB = ((const int4*)gp)[1];
      uint8_t* base = (uint8_t*)ldsB + rowB * 64;
      *(uint4*)(base + ((halfB * 2 + 0) ^ swzB) * 16) =
          make_uint4(dq(wA.x, ph, pl), dq(wA.y, ph, pl),
                     dq(wA.z, ph, pl), dq(wA.w, ph, pl));
      *(uint4*)(base + ((halfB * 2 + 1) ^ swzB) * 16) =
          make_uint4(dq(wB.x, ph, pl), dq(wB.y, ph, pl),
                     dq(wB.z, ph, pl), dq(wB.w, ph, pl));
    }

    __syncthreads();

    const int q = lane >> 4;
    half8 af[4], bfr[4];
#pragma unroll
    for (int i = 0; i < 4; ++i) {
      const int row = wm * 64 + i * 16 + (lane & 15);
      af[i] = *(const half8*)(ldsA + row * BK + (q ^ ((row >> 1) & 3)) * 8);
    }
#pragma unroll
    for (int j = 0; j < 4; ++j) {
      const int row = wn * 64 + j * 16 + (lane & 15);
      bfr[j] = *(const half8*)(ldsB + row * BK + (q ^ ((row >> 1) & 3)) * 8);
    }
#pragma unroll
    for (int i = 0; i < 4; ++i)
#pragma unroll
      for (int j = 0; j < 4; ++j)
        acc[i][j] = __builtin_amdgcn_mfma_f32_16x16x32_f16(af[i], bfr[j], acc[i][j], 0, 0, 0);
  }

  const int mb = m0 + wm * 64 + (lane >> 4) * 4;
  const int nb = n0 + wn * 64 + (lane & 15);
#pragma unroll
  for (int i = 0; i < 4; ++i)
#pragma unroll
    for (int j = 0; j < 4; ++j)
#pragma unroll
      for (int r = 0; r < 4; ++r)
        out[(size_t)(mb + i * 16 + r) * N_DIM + (nb + j * 16)] = acc[i][j][r];
}

extern "C" void kernel_launch(void* const* d_in, const int* in_sizes, int n_in,
                              void* d_out, int out_size, void* d_ws, size_t ws_size,
                              hipStream_t stream) {
  // Size-based dispatch (element counts are dtype-independent and unique).
  const void* px = nullptr; const void* ppw = nullptr; const void* plut = nullptr;
  for (int i = 0; i < n_in; ++i) {
    const long s = in_sizes[i];
    if (s == (long)M_DIM * K_DIM) px = d_in[i];
    else if (s == (long)N_DIM * KW) ppw = d_in[i];
    else if (s == 16) plut = d_in[i];
  }
  if (!px || !ppw || !plut) { px = d_in[0]; ppw = d_in[1]; plut = d_in[2]; }

  if (ws_size >= WS_XH_BYTES + WS_WH_BYTES) {
    // Fused prep: x f32->f16 into ws[0,32MB) and W fp4->f16 into ws[32MB,64MB).
    uint8_t* wh = (uint8_t*)d_ws + WS_XH_BYTES;
    prep_kernel<<<XBLOCKS + WBLOCKS, 256, 0, stream>>>(
        (const float4*)px, (uint4*)d_ws, (const int4*)ppw, (uint4*)wh,
        (const float*)plut);
    f16gemm256_kernel<<<dim3(256), dim3(512), 0, stream>>>(
        (const uint8_t*)d_ws, wh, (float*)d_out);
  } else {
    cvt_x_kernel<<<(M_DIM * K_DIM / 8) / 256, 256, 0, stream>>>(
        (const float4*)px, (uint4*)d_ws);
    dim3 grid(N_DIM / BN, M_DIM / BM);
    fp4gemm_kernel<<<grid, dim3(256), 0, stream>>>(
        (const uint8_t*)d_ws, (const int*)ppw, (const float*)plut, (float*)d_out);
  }
}